// Round 9
// baseline (796.246 us; speedup 1.0000x reference)
//
#include <hip/hip_runtime.h>
#include <hip/hip_cooperative_groups.h>

namespace cg = cooperative_groups;

typedef float f32x4 __attribute__((ext_vector_type(4)));
typedef _Float16 f16x8 __attribute__((ext_vector_type(8)));
typedef _Float16 v2h __attribute__((ext_vector_type(2)));
typedef short s16x2 __attribute__((ext_vector_type(2)));

__device__ __forceinline__ float hdot2(v2h a, v2h b, float c) {
#if __has_builtin(__builtin_amdgcn_fdot2)
  return __builtin_amdgcn_fdot2(a, b, c, false);
#else
  return c + (float)a[0] * (float)b[0] + (float)a[1] * (float)b[1];
#endif
}

__device__ __forceinline__ v2h relu2(v2h a) {
#if __has_builtin(__builtin_elementwise_max)
  const v2h z = {(_Float16)0, (_Float16)0};
  return __builtin_elementwise_max(a, z);
#else
  const v2h z = {(_Float16)0, (_Float16)0};
  s16x2 m = a > z;
  s16x2 bits = *(s16x2*)&a;
  s16x2 r = bits & m;
  return *(v2h*)&r;
#endif
}

// ---------------------------------------------------------------------------
// Entire counting sort in ONE cooperative dispatch:
//   zero deg -> hist -> scan(p1/p2/p3) -> scatter(int2 payload)
// 1024 blocks x 256 thr, __launch_bounds__(256,4) => 4 blocks/CU co-resident.
// ---------------------------------------------------------------------------
__global__ __launch_bounds__(256, 4) void sort_coop(
    const int* __restrict__ edge_obj, const int* __restrict__ edge_sub,
    const int* __restrict__ edge_rel, const int* __restrict__ r_idx,
    const int* __restrict__ q_rel, int* deg, int* bsum, int* bbase,
    int* offs, int* curs, int2* ssrq, int E, int n, int nb) {
  cg::grid_group grid = cg::this_grid();
  __shared__ int s[512];
  const int tid = blockIdx.x * 256 + threadIdx.x;
  const int nthr = gridDim.x * 256;
  const int t = threadIdx.x;
  const int b = blockIdx.x;

  // phase 0: zero degree counters
  for (int i = tid; i < n; i += nthr) deg[i] = 0;
  grid.sync();

  // phase 1: histogram
  for (int i = tid; i < E; i += nthr) atomicAdd(&deg[edge_obj[i]], 1);
  grid.sync();

  // phase 2 (p1): per-block chunk sums (512 nodes/block), blocks [0, nb)
  if (b < nb) {
    const int i0 = b * 512 + t, i1 = i0 + 256;
    int v = 0;
    if (i0 < n) v += deg[i0];
    if (i1 < n) v += deg[i1];
    s[t] = v;
    __syncthreads();
    for (int o = 128; o > 0; o >>= 1) {
      if (t < o) s[t] += s[t + o];
      __syncthreads();
    }
    if (t == 0) bsum[b] = s[0];
  }
  grid.sync();

  // phase 3 (p2): block 0 scans the nb (<=256) block sums
  if (b == 0) {
    const int v = (t < nb) ? bsum[t] : 0;
    s[t] = v;
    __syncthreads();
    for (int o = 1; o < 256; o <<= 1) {
      const int a = (t >= o) ? s[t - o] : 0;
      __syncthreads();
      s[t] += a;
      __syncthreads();
    }
    if (t < nb) bbase[t] = s[t] - v;
    if (t == 255) offs[n] = s[255];
  }
  grid.sync();

  // phase 4 (p3): per-chunk local exclusive scan + base -> offs, curs
  if (b < nb) {
    const int i0 = b * 512 + t, i1 = i0 + 256;
    const int d0 = (i0 < n) ? deg[i0] : 0;
    const int d1 = (i1 < n) ? deg[i1] : 0;
    s[t] = d0;
    s[t + 256] = d1;
    __syncthreads();
    for (int o = 1; o < 512; o <<= 1) {
      const int a0 = (t >= o) ? s[t - o] : 0;
      const int a1 = (t + 256 >= o) ? s[t + 256 - o] : 0;
      __syncthreads();
      s[t] += a0;
      s[t + 256] += a1;
      __syncthreads();
    }
    const int base = bbase[b];
    if (i0 < n) { const int e = base + s[t] - d0;       offs[i0] = e; curs[i0] = e; }
    if (i1 < n) { const int e = base + s[t + 256] - d1; offs[i1] = e; curs[i1] = e; }
  }
  grid.sync();

  // phase 5: scatter pre-gathered payload to sorted position
  for (int i = tid; i < E; i += nthr) {
    const int p = atomicAdd(&curs[edge_obj[i]], 1);
    ssrq[p] = make_int2(edge_sub[i], (edge_rel[i] << 9) | q_rel[r_idx[i]]);
  }
}

// ---------------------------------------------------------------------------
// Unified prep GEMM (one dispatch, 3 roles by block index):
//  role 0 (blocks [0,hid)):        Hcat.lo = fp16(hidden); Hcat.hi = hidden@Ws
//  role 1 (blocks [hid,hid+rb)):   Rcat.lo = fp16(rela);   Rcat.hi = rela@Wr
//  role 2 (blocks [hid+rb,+rb)):   Rwqrt = rela@Wqr + b
// Each block stages its own W f32 -> fp16 transposed/k-grouped LDS.
// ---------------------------------------------------------------------------
__global__ __launch_bounds__(256) void prep_gemm(
    const float* __restrict__ hidden, const float* __restrict__ rela,
    const float* __restrict__ Ws, const float* __restrict__ Wr,
    const float* __restrict__ Wqr, const float* __restrict__ Wqr_b,
    _Float16* __restrict__ Hcat, _Float16* __restrict__ Rcat,
    _Float16* __restrict__ Rwqrt, int n_node, int n_rel,
    int hid_blocks, int rel_blocks) {
  __shared__ _Float16 sW[16384];
  const int bidx = blockIdx.x;
  const float* A;
  const float* W;
  const float* bias = nullptr;
  _Float16* Lo = nullptr;
  _Float16* Chi;
  int M, bb, ldc, coff;
  if (bidx < hid_blocks) {
    bb = bidx; A = hidden; W = Ws; Lo = Hcat; Chi = Hcat;
    M = n_node; ldc = 256; coff = 128;
  } else if (bidx < hid_blocks + rel_blocks) {
    bb = bidx - hid_blocks; A = rela; W = Wr; Lo = Rcat; Chi = Rcat;
    M = n_rel; ldc = 256; coff = 128;
  } else {
    bb = bidx - hid_blocks - rel_blocks; A = rela; W = Wqr; Chi = Rwqrt;
    bias = Wqr_b; M = n_rel; ldc = 128; coff = 0;
  }

  // stage W: f32 [k][c] -> fp16 LDS [(k>>3)*1024 + c*8 + (k&7)]
  for (int i = threadIdx.x; i < 16384; i += 256) {
    const int k = i >> 7, c = i & 127;
    sW[(k >> 3) * 1024 + c * 8 + (k & 7)] = (_Float16)W[i];
  }
  __syncthreads();

  const int wv = threadIdx.x >> 6, l = threadIdx.x & 63;
  const int row = bb * 64 + wv * 16 + (l & 15);
  const int kb = (l >> 4) * 8;
  const bool rvalid = row < M;

  f16x8 a[4];
#pragma unroll
  for (int kk = 0; kk < 4; ++kk) {
    f16x8 t = {0, 0, 0, 0, 0, 0, 0, 0};
    if (rvalid) {
      const f32x4 lo = *(const f32x4*)(A + (size_t)row * 128 + kb + 32 * kk);
      const f32x4 hi = *(const f32x4*)(A + (size_t)row * 128 + kb + 32 * kk + 4);
      t[0] = (_Float16)lo[0]; t[1] = (_Float16)lo[1];
      t[2] = (_Float16)lo[2]; t[3] = (_Float16)lo[3];
      t[4] = (_Float16)hi[0]; t[5] = (_Float16)hi[1];
      t[6] = (_Float16)hi[2]; t[7] = (_Float16)hi[3];
      if (Lo) *(f16x8*)(Lo + (size_t)row * 256 + kb + 32 * kk) = t;
    }
    a[kk] = t;
  }

  f32x4 acc[8];
#pragma unroll
  for (int n = 0; n < 8; ++n) acc[n] = (f32x4){0.f, 0.f, 0.f, 0.f};
#pragma unroll
  for (int n = 0; n < 8; ++n)
#pragma unroll
    for (int kk = 0; kk < 4; ++kk) {
      const int kg = 4 * kk + (l >> 4);
      const f16x8 bfrag = *(const f16x8*)(sW + kg * 1024 + (16 * n + (l & 15)) * 8);
      acc[n] = __builtin_amdgcn_mfma_f32_16x16x32_f16(a[kk], bfrag, acc[n], 0, 0, 0);
    }

  const int orow_base = bb * 64 + wv * 16 + (l >> 4) * 4;
#pragma unroll
  for (int n = 0; n < 8; ++n) {
    const int col = 16 * n + (l & 15);
    const float badd = bias ? bias[col] : 0.0f;
#pragma unroll
    for (int r4 = 0; r4 < 4; ++r4) {
      const int orow = orow_base + r4;
      if (orow < M)
        Chi[(size_t)orow * ldc + coff + col] = (_Float16)(acc[n][r4] + badd);
    }
  }
}

// ---------------------------------------------------------------------------
// Final projection: out[M,128] f32 = agg fp16 @ Wh (Wh staged f32->fp16 LDS).
// ---------------------------------------------------------------------------
__global__ __launch_bounds__(256) void gemm_final(
    const _Float16* __restrict__ agg, const float* __restrict__ Wh,
    float* __restrict__ out, int M) {
  __shared__ _Float16 sW[16384];
  for (int i = threadIdx.x; i < 16384; i += 256) {
    const int k = i >> 7, c = i & 127;
    sW[(k >> 3) * 1024 + c * 8 + (k & 7)] = (_Float16)Wh[i];
  }
  __syncthreads();

  const int wv = threadIdx.x >> 6, l = threadIdx.x & 63;
  const int row = blockIdx.x * 64 + wv * 16 + (l & 15);
  const int kb = (l >> 4) * 8;
  const bool rvalid = row < M;

  f16x8 a[4];
#pragma unroll
  for (int kk = 0; kk < 4; ++kk) {
    f16x8 t = {0, 0, 0, 0, 0, 0, 0, 0};
    if (rvalid) t = *(const f16x8*)(agg + (size_t)row * 128 + kb + 32 * kk);
    a[kk] = t;
  }

  f32x4 acc[8];
#pragma unroll
  for (int n = 0; n < 8; ++n) acc[n] = (f32x4){0.f, 0.f, 0.f, 0.f};
#pragma unroll
  for (int n = 0; n < 8; ++n)
#pragma unroll
    for (int kk = 0; kk < 4; ++kk) {
      const int kg = 4 * kk + (l >> 4);
      const f16x8 bfrag = *(const f16x8*)(sW + kg * 1024 + (16 * n + (l & 15)) * 8);
      acc[n] = __builtin_amdgcn_mfma_f32_16x16x32_f16(a[kk], bfrag, acc[n], 0, 0, 0);
    }

  const int orow_base = blockIdx.x * 64 + wv * 16 + (l >> 4) * 4;
#pragma unroll
  for (int n = 0; n < 8; ++n) {
    const int col = 16 * n + (l & 15);
#pragma unroll
    for (int r4 = 0; r4 < 4; ++r4) {
      const int orow = orow_base + r4;
      if (orow < M) out[(size_t)orow * 128 + col] = acc[n][r4];
    }
  }
}

// ---------------------------------------------------------------------------
// Per-node gather-reduce, fp16 packed math. One wave per node; 4 edges x 16
// lanes; lane owns dims [8*(l&15), +8). agg fp16 (ld 128). (unchanged, R8)
// ---------------------------------------------------------------------------
__global__ __launch_bounds__(256) void reduce_f16(
    const int2* __restrict__ ssrq, const int* __restrict__ offs,
    const _Float16* __restrict__ Hcat, const _Float16* __restrict__ Rcat,
    const _Float16* __restrict__ Rwqrt, const float* __restrict__ wa_w,
    const float* __restrict__ wa_b_p, _Float16* __restrict__ agg, int n_node) {
  const int node = (blockIdx.x * blockDim.x + threadIdx.x) >> 6;
  if (node >= n_node) return;
  const int l = threadIdx.x & 63;
  const int g = l >> 4;
  const int d0 = (l & 15) * 8;

  v2h wa2[4];
  {
    const float4 w0 = *(const float4*)(wa_w + d0);
    const float4 w1 = *(const float4*)(wa_w + d0 + 4);
    wa2[0] = (v2h){(_Float16)w0.x, (_Float16)w0.y};
    wa2[1] = (v2h){(_Float16)w0.z, (_Float16)w0.w};
    wa2[2] = (v2h){(_Float16)w1.x, (_Float16)w1.y};
    wa2[3] = (v2h){(_Float16)w1.z, (_Float16)w1.w};
  }
  const float wab = wa_b_p[0];

  const int start = offs[node], end = offs[node + 1];
  v2h acc2[4] = {};

  for (int base = start; base < end; base += 64) {
    const int cnt = min(end - base, 64);
    int s_all = 0, rq_all = 0;
    if (l < cnt) { const int2 sr = ssrq[base + l]; s_all = sr.x; rq_all = sr.y; }
    for (int c = 0; c < cnt; c += 4) {
      const int src = c + g;
      const bool valid = src < cnt;
      const int sv = __shfl(s_all, src);
      const int rqv = __shfl(rq_all, src);
      const int rv = rqv >> 9, qv = rqv & 511;

      f32x4 rw = *(const f32x4*)(Hcat + ((size_t)sv << 8) + 128 + d0);
      f32x4 rr = *(const f32x4*)(Rcat + ((size_t)rv << 8) + 128 + d0);
      f32x4 rq = *(const f32x4*)(Rwqrt + ((size_t)qv << 7) + d0);
      f32x4 rh = *(const f32x4*)(Hcat + ((size_t)sv << 8) + d0);
      f32x4 rg = *(const f32x4*)(Rcat + ((size_t)rv << 8) + d0);
      const v2h* hw = (const v2h*)&rw;
      const v2h* hr_ = (const v2h*)&rr;
      const v2h* hq = (const v2h*)&rq;
      const v2h* hh = (const v2h*)&rh;
      const v2h* hg = (const v2h*)&rg;

      float part = 0.0f;
      v2h prod[4];
#pragma unroll
      for (int i = 0; i < 4; ++i) {
        const v2h pre = relu2(hw[i] + hr_[i] + hq[i]);
        part = hdot2(pre, wa2[i], part);
        prod[i] = hh[i] * hg[i];
      }
      part += __shfl_xor(part, 1);
      part += __shfl_xor(part, 2);
      part += __shfl_xor(part, 4);
      part += __shfl_xor(part, 8);
      const float alpha = valid ? 1.0f / (1.0f + __expf(-(part + wab))) : 0.0f;
      const _Float16 ah = (_Float16)alpha;
      const v2h alpha2 = {ah, ah};
#pragma unroll
      for (int i = 0; i < 4; ++i) acc2[i] += alpha2 * prod[i];
    }
  }

#pragma unroll
  for (int i = 0; i < 4; ++i) {
    unsigned x = *(unsigned*)&acc2[i];
    unsigned y = (unsigned)__shfl_xor((int)x, 16);
    acc2[i] += *(v2h*)&y;
    x = *(unsigned*)&acc2[i];
    y = (unsigned)__shfl_xor((int)x, 32);
    acc2[i] += *(v2h*)&y;
  }
  if (l < 16)
    *(f32x4*)(agg + (size_t)node * 128 + d0) = *(f32x4*)acc2;
}

// ---------------------------------------------------------------------------
extern "C" void kernel_launch(void* const* d_in, const int* in_sizes, int n_in,
                              void* d_out, int out_size, void* d_ws, size_t ws_size,
                              hipStream_t stream) {
  const int* q_rel = (const int*)d_in[1];
  const int* r_idx = (const int*)d_in[2];
  const float* hidden = (const float*)d_in[3];
  const int* edge_sub = (const int*)d_in[4];
  const int* edge_rel = (const int*)d_in[5];
  const int* edge_obj = (const int*)d_in[6];
  const float* rela = (const float*)d_in[8];
  const float* Ws = (const float*)d_in[9];
  const float* Wr = (const float*)d_in[10];
  const float* Wqr_w = (const float*)d_in[11];
  const float* Wqr_b = (const float*)d_in[12];
  const float* wa_w = (const float*)d_in[13];
  const float* wa_b = (const float*)d_in[14];
  const float* Wh = (const float*)d_in[15];

  int E = in_sizes[2];
  int n_node = in_sizes[3] / 128;
  const int n_rel = in_sizes[8] / 128;
  float* out = (float*)d_out;

  auto al = [](size_t x) { return (x + 511) & ~(size_t)511; };
  char* ws = (char*)d_ws;
  size_t o = 0;
  _Float16* Hcat = (_Float16*)(ws + o);  o += al((size_t)n_node * 256 * 2);
  _Float16* agg  = (_Float16*)(ws + o);  o += al((size_t)n_node * 128 * 2);
  _Float16* Rcat = (_Float16*)(ws + o);  o += al((size_t)n_rel * 256 * 2);
  _Float16* Rwqrt = (_Float16*)(ws + o); o += al((size_t)n_rel * 128 * 2);
  int* deg = (int*)(ws + o);       o += al((size_t)n_node * 4);
  int* offs = (int*)(ws + o);      o += al((size_t)(n_node + 1) * 4);
  int* curs = (int*)(ws + o);      o += al((size_t)n_node * 4);
  int* bsum = (int*)(ws + o);      o += al(1024 * 4);
  int* bbase = (int*)(ws + o);     o += al(1024 * 4);
  int2* ssrq = (int2*)(ws + o);    o += al((size_t)E * 8);

  // --- 1: whole counting sort in one cooperative dispatch ---
  int nb = (n_node + 511) / 512;  // 98 <= 256
  {
    void* args[] = {(void*)&edge_obj, (void*)&edge_sub, (void*)&edge_rel,
                    (void*)&r_idx,    (void*)&q_rel,    (void*)&deg,
                    (void*)&bsum,     (void*)&bbase,    (void*)&offs,
                    (void*)&curs,     (void*)&ssrq,     (void*)&E,
                    (void*)&n_node,   (void*)&nb};
    (void)hipLaunchCooperativeKernel((void*)sort_coop, dim3(1024), dim3(256),
                                     args, 0, stream);
  }

  // --- 2: unified prep (hidden conv+proj, rela conv+2 proj) ---
  const int hid_blocks = (n_node + 63) / 64;
  const int rel_blocks = (n_rel + 63) / 64;
  prep_gemm<<<dim3(hid_blocks + 2 * rel_blocks), dim3(256), 0, stream>>>(
      hidden, rela, Ws, Wr, Wqr_w, Wqr_b, Hcat, Rcat, Rwqrt,
      n_node, n_rel, hid_blocks, rel_blocks);

  // --- 3: fused attention + aggregation ---
  const int rblocks = (n_node * 64 + 255) / 256;
  reduce_f16<<<dim3(rblocks), dim3(256), 0, stream>>>(
      ssrq, offs, Hcat, Rcat, Rwqrt, wa_w, wa_b, agg, n_node);

  // --- 4: final projection ---
  gemm_final<<<dim3(hid_blocks), dim3(256), 0, stream>>>(agg, Wh, out, n_node);
}

// Round 10
// 414.517 us; speedup vs baseline: 1.9209x; 1.9209x over previous
//
#include <hip/hip_runtime.h>

typedef float f32x4 __attribute__((ext_vector_type(4)));
typedef _Float16 f16x8 __attribute__((ext_vector_type(8)));
typedef _Float16 v2h __attribute__((ext_vector_type(2)));
typedef short s16x2 __attribute__((ext_vector_type(2)));

__device__ __forceinline__ float hdot2(v2h a, v2h b, float c) {
#if __has_builtin(__builtin_amdgcn_fdot2)
  return __builtin_amdgcn_fdot2(a, b, c, false);
#else
  return c + (float)a[0] * (float)b[0] + (float)a[1] * (float)b[1];
#endif
}

__device__ __forceinline__ v2h relu2(v2h a) {
#if __has_builtin(__builtin_elementwise_max)
  const v2h z = {(_Float16)0, (_Float16)0};
  return __builtin_elementwise_max(a, z);
#else
  const v2h z = {(_Float16)0, (_Float16)0};
  s16x2 m = a > z;
  s16x2 bits = *(s16x2*)&a;
  s16x2 r = bits & m;
  return *(v2h*)&r;
#endif
}

// ---------------------------------------------------------------------------
// K1: per-(bucket, group) histogram. bucket = obj>>9 (512 nodes each),
// group = blockIdx&7 (XCD-locality heuristic; correctness independent).
// LDS-aggregated, one global atomic per (block, bucket).
// ---------------------------------------------------------------------------
__global__ __launch_bounds__(256) void bucket_hist(const int* __restrict__ eobj,
                                                   int* __restrict__ bhist,
                                                   int E, int nbkt) {
  __shared__ int lh[128];
  const int g = blockIdx.x & 7;
  for (int i = threadIdx.x; i < nbkt; i += 256) lh[i] = 0;
  __syncthreads();
  for (int i = blockIdx.x * 256 + threadIdx.x; i < E; i += gridDim.x * 256)
    atomicAdd(&lh[eobj[i] >> 9], 1);
  __syncthreads();
  for (int i = threadIdx.x; i < nbkt; i += 256)
    if (lh[i]) atomicAdd(&bhist[i * 8 + g], lh[i]);
}

// ---------------------------------------------------------------------------
// K2: one block scans the nbkt*8 (<=1024) counters -> bcur (exclusive),
// bucket starts bstart[b] (= prefix at b*8), bstart[nbkt]=E, offs[n]=E.
// ---------------------------------------------------------------------------
__global__ __launch_bounds__(256) void bucket_scan(const int* __restrict__ bhist,
                                                   int* __restrict__ bcur,
                                                   int* __restrict__ bstart,
                                                   int* __restrict__ offs,
                                                   int nbkt, int n, int E) {
  const int t = threadIdx.x;
  const int total = nbkt * 8;
  const int CH = (total + 255) / 256;  // <=8
  const int lo = t * CH, hi = min(lo + CH, total);
  int vals[8];
  int sum = 0;
  for (int i = lo; i < hi; ++i) { vals[i - lo] = bhist[i]; sum += vals[i - lo]; }
  __shared__ int s[256];
  s[t] = sum;
  __syncthreads();
  for (int o = 1; o < 256; o <<= 1) {
    const int a = (t >= o) ? s[t - o] : 0;
    __syncthreads();
    s[t] += a;
    __syncthreads();
  }
  int run = s[t] - sum;
  for (int i = lo; i < hi; ++i) {
    if ((i & 7) == 0) bstart[i >> 3] = run;
    bcur[i] = run;
    run += vals[i - lo];
  }
  if (t == 0) { bstart[nbkt] = E; offs[n] = E; }
}

// ---------------------------------------------------------------------------
// K3: scatter pre-gathered payload into (bucket,group) regions.
// payload.y packs rel<<18 | qr<<9 | lobj  (475<512, 512 nodes/bucket).
// MUST use the same grid dims / group formula as K1.
// ---------------------------------------------------------------------------
__global__ __launch_bounds__(256) void bucket_scatter(
    const int* __restrict__ eobj, const int* __restrict__ esub,
    const int* __restrict__ erel, const int* __restrict__ ridx,
    const int* __restrict__ qrel, int* __restrict__ bcur,
    int2* __restrict__ tmp, int E) {
  const int g = blockIdx.x & 7;
  for (int i = blockIdx.x * 256 + threadIdx.x; i < E; i += gridDim.x * 256) {
    const int obj = eobj[i];
    const int b = obj >> 9, lobj = obj & 511;
    const int p = atomicAdd(&bcur[b * 8 + g], 1);
    tmp[p] = make_int2(esub[i], (erel[i] << 18) | (qrel[ridx[i]] << 9) | lobj);
  }
}

// ---------------------------------------------------------------------------
// K4: one block per bucket. Count per-node in LDS -> scan -> write offs ->
// scatter into LDS stage -> coalesced write of final (sub, rel<<9|qr) CSR.
// Fallback to direct global scatter if bucket > 8192 edges.
// ---------------------------------------------------------------------------
__global__ __launch_bounds__(256) void bucket_sort(
    const int2* __restrict__ tmp, const int* __restrict__ bstart,
    int* __restrict__ offs, int2* __restrict__ ssrq, int n) {
  __shared__ int2 stage[8192];
  __shared__ int scnt[512];
  __shared__ int scur[512];
  const int b = blockIdx.x, t = threadIdx.x;
  const int s0 = bstart[b], s1 = bstart[b + 1];
  const int cnt = s1 - s0;
  const int node0 = b * 512;

  scnt[t] = 0;
  scnt[t + 256] = 0;
  __syncthreads();
  for (int i = t; i < cnt; i += 256) atomicAdd(&scnt[tmp[s0 + i].y & 511], 1);
  __syncthreads();

  const int d0 = scnt[t], d1 = scnt[t + 256];
  __syncthreads();
  for (int o = 1; o < 512; o <<= 1) {
    const int a0 = (t >= o) ? scnt[t - o] : 0;
    const int a1 = (t + 256 >= o) ? scnt[t + 256 - o] : 0;
    __syncthreads();
    scnt[t] += a0;
    scnt[t + 256] += a1;
    __syncthreads();
  }
  const int e0 = scnt[t] - d0, e1 = scnt[t + 256] - d1;
  scur[t] = e0;
  scur[t + 256] = e1;
  if (node0 + t < n) offs[node0 + t] = s0 + e0;
  if (node0 + t + 256 < n) offs[node0 + t + 256] = s0 + e1;
  __syncthreads();

  if (cnt <= 8192) {
    for (int i = t; i < cnt; i += 256) {
      const int2 p = tmp[s0 + i];
      const int q = atomicAdd(&scur[p.y & 511], 1);
      stage[q] = make_int2(p.x, p.y >> 9);
    }
    __syncthreads();
    for (int i = t; i < cnt; i += 256) ssrq[s0 + i] = stage[i];
  } else {
    for (int i = t; i < cnt; i += 256) {
      const int2 p = tmp[s0 + i];
      const int q = atomicAdd(&scur[p.y & 511], 1);
      ssrq[s0 + q] = make_int2(p.x, p.y >> 9);
    }
  }
}

// ---------------------------------------------------------------------------
// Unified prep GEMM (3 roles by block index), W staged f32->fp16 LDS.
// ---------------------------------------------------------------------------
__global__ __launch_bounds__(256) void prep_gemm(
    const float* __restrict__ hidden, const float* __restrict__ rela,
    const float* __restrict__ Ws, const float* __restrict__ Wr,
    const float* __restrict__ Wqr, const float* __restrict__ Wqr_b,
    _Float16* __restrict__ Hcat, _Float16* __restrict__ Rcat,
    _Float16* __restrict__ Rwqrt, int n_node, int n_rel,
    int hid_blocks, int rel_blocks) {
  __shared__ _Float16 sW[16384];
  const int bidx = blockIdx.x;
  const float* A;
  const float* W;
  const float* bias = nullptr;
  _Float16* Lo = nullptr;
  _Float16* Chi;
  int M, bb, ldc, coff;
  if (bidx < hid_blocks) {
    bb = bidx; A = hidden; W = Ws; Lo = Hcat; Chi = Hcat;
    M = n_node; ldc = 256; coff = 128;
  } else if (bidx < hid_blocks + rel_blocks) {
    bb = bidx - hid_blocks; A = rela; W = Wr; Lo = Rcat; Chi = Rcat;
    M = n_rel; ldc = 256; coff = 128;
  } else {
    bb = bidx - hid_blocks - rel_blocks; A = rela; W = Wqr; Chi = Rwqrt;
    bias = Wqr_b; M = n_rel; ldc = 128; coff = 0;
  }

  for (int i = threadIdx.x; i < 16384; i += 256) {
    const int k = i >> 7, c = i & 127;
    sW[(k >> 3) * 1024 + c * 8 + (k & 7)] = (_Float16)W[i];
  }
  __syncthreads();

  const int wv = threadIdx.x >> 6, l = threadIdx.x & 63;
  const int row = bb * 64 + wv * 16 + (l & 15);
  const int kb = (l >> 4) * 8;
  const bool rvalid = row < M;

  f16x8 a[4];
#pragma unroll
  for (int kk = 0; kk < 4; ++kk) {
    f16x8 t = {0, 0, 0, 0, 0, 0, 0, 0};
    if (rvalid) {
      const f32x4 lo = *(const f32x4*)(A + (size_t)row * 128 + kb + 32 * kk);
      const f32x4 hi = *(const f32x4*)(A + (size_t)row * 128 + kb + 32 * kk + 4);
      t[0] = (_Float16)lo[0]; t[1] = (_Float16)lo[1];
      t[2] = (_Float16)lo[2]; t[3] = (_Float16)lo[3];
      t[4] = (_Float16)hi[0]; t[5] = (_Float16)hi[1];
      t[6] = (_Float16)hi[2]; t[7] = (_Float16)hi[3];
      if (Lo) *(f16x8*)(Lo + (size_t)row * 256 + kb + 32 * kk) = t;
    }
    a[kk] = t;
  }

  f32x4 acc[8];
#pragma unroll
  for (int n = 0; n < 8; ++n) acc[n] = (f32x4){0.f, 0.f, 0.f, 0.f};
#pragma unroll
  for (int n = 0; n < 8; ++n)
#pragma unroll
    for (int kk = 0; kk < 4; ++kk) {
      const int kg = 4 * kk + (l >> 4);
      const f16x8 bfrag = *(const f16x8*)(sW + kg * 1024 + (16 * n + (l & 15)) * 8);
      acc[n] = __builtin_amdgcn_mfma_f32_16x16x32_f16(a[kk], bfrag, acc[n], 0, 0, 0);
    }

  const int orow_base = bb * 64 + wv * 16 + (l >> 4) * 4;
#pragma unroll
  for (int n = 0; n < 8; ++n) {
    const int col = 16 * n + (l & 15);
    const float badd = bias ? bias[col] : 0.0f;
#pragma unroll
    for (int r4 = 0; r4 < 4; ++r4) {
      const int orow = orow_base + r4;
      if (orow < M)
        Chi[(size_t)orow * ldc + coff + col] = (_Float16)(acc[n][r4] + badd);
    }
  }
}

// ---------------------------------------------------------------------------
// Final projection: out f32 = agg fp16 @ Wh (Wh staged f32->fp16 LDS).
// ---------------------------------------------------------------------------
__global__ __launch_bounds__(256) void gemm_final(
    const _Float16* __restrict__ agg, const float* __restrict__ Wh,
    float* __restrict__ out, int M) {
  __shared__ _Float16 sW[16384];
  for (int i = threadIdx.x; i < 16384; i += 256) {
    const int k = i >> 7, c = i & 127;
    sW[(k >> 3) * 1024 + c * 8 + (k & 7)] = (_Float16)Wh[i];
  }
  __syncthreads();

  const int wv = threadIdx.x >> 6, l = threadIdx.x & 63;
  const int row = blockIdx.x * 64 + wv * 16 + (l & 15);
  const int kb = (l >> 4) * 8;
  const bool rvalid = row < M;

  f16x8 a[4];
#pragma unroll
  for (int kk = 0; kk < 4; ++kk) {
    f16x8 t = {0, 0, 0, 0, 0, 0, 0, 0};
    if (rvalid) t = *(const f16x8*)(agg + (size_t)row * 128 + kb + 32 * kk);
    a[kk] = t;
  }

  f32x4 acc[8];
#pragma unroll
  for (int n = 0; n < 8; ++n) acc[n] = (f32x4){0.f, 0.f, 0.f, 0.f};
#pragma unroll
  for (int n = 0; n < 8; ++n)
#pragma unroll
    for (int kk = 0; kk < 4; ++kk) {
      const int kg = 4 * kk + (l >> 4);
      const f16x8 bfrag = *(const f16x8*)(sW + kg * 1024 + (16 * n + (l & 15)) * 8);
      acc[n] = __builtin_amdgcn_mfma_f32_16x16x32_f16(a[kk], bfrag, acc[n], 0, 0, 0);
    }

  const int orow_base = blockIdx.x * 64 + wv * 16 + (l >> 4) * 4;
#pragma unroll
  for (int n = 0; n < 8; ++n) {
    const int col = 16 * n + (l & 15);
#pragma unroll
    for (int r4 = 0; r4 < 4; ++r4) {
      const int orow = orow_base + r4;
      if (orow < M) out[(size_t)orow * 128 + col] = acc[n][r4];
    }
  }
}

// ---------------------------------------------------------------------------
// Per-node gather-reduce, fp16 packed math (unchanged from R8).
// ---------------------------------------------------------------------------
__global__ __launch_bounds__(256) void reduce_f16(
    const int2* __restrict__ ssrq, const int* __restrict__ offs,
    const _Float16* __restrict__ Hcat, const _Float16* __restrict__ Rcat,
    const _Float16* __restrict__ Rwqrt, const float* __restrict__ wa_w,
    const float* __restrict__ wa_b_p, _Float16* __restrict__ agg, int n_node) {
  const int node = (blockIdx.x * blockDim.x + threadIdx.x) >> 6;
  if (node >= n_node) return;
  const int l = threadIdx.x & 63;
  const int g = l >> 4;
  const int d0 = (l & 15) * 8;

  v2h wa2[4];
  {
    const float4 w0 = *(const float4*)(wa_w + d0);
    const float4 w1 = *(const float4*)(wa_w + d0 + 4);
    wa2[0] = (v2h){(_Float16)w0.x, (_Float16)w0.y};
    wa2[1] = (v2h){(_Float16)w0.z, (_Float16)w0.w};
    wa2[2] = (v2h){(_Float16)w1.x, (_Float16)w1.y};
    wa2[3] = (v2h){(_Float16)w1.z, (_Float16)w1.w};
  }
  const float wab = wa_b_p[0];

  const int start = offs[node], end = offs[node + 1];
  v2h acc2[4] = {};

  for (int base = start; base < end; base += 64) {
    const int cnt = min(end - base, 64);
    int s_all = 0, rq_all = 0;
    if (l < cnt) { const int2 sr = ssrq[base + l]; s_all = sr.x; rq_all = sr.y; }
    for (int c = 0; c < cnt; c += 4) {
      const int src = c + g;
      const bool valid = src < cnt;
      const int sv = __shfl(s_all, src);
      const int rqv = __shfl(rq_all, src);
      const int rv = rqv >> 9, qv = rqv & 511;

      f32x4 rw = *(const f32x4*)(Hcat + ((size_t)sv << 8) + 128 + d0);
      f32x4 rr = *(const f32x4*)(Rcat + ((size_t)rv << 8) + 128 + d0);
      f32x4 rq = *(const f32x4*)(Rwqrt + ((size_t)qv << 7) + d0);
      f32x4 rh = *(const f32x4*)(Hcat + ((size_t)sv << 8) + d0);
      f32x4 rg = *(const f32x4*)(Rcat + ((size_t)rv << 8) + d0);
      const v2h* hw = (const v2h*)&rw;
      const v2h* hr_ = (const v2h*)&rr;
      const v2h* hq = (const v2h*)&rq;
      const v2h* hh = (const v2h*)&rh;
      const v2h* hg = (const v2h*)&rg;

      float part = 0.0f;
      v2h prod[4];
#pragma unroll
      for (int i = 0; i < 4; ++i) {
        const v2h pre = relu2(hw[i] + hr_[i] + hq[i]);
        part = hdot2(pre, wa2[i], part);
        prod[i] = hh[i] * hg[i];
      }
      part += __shfl_xor(part, 1);
      part += __shfl_xor(part, 2);
      part += __shfl_xor(part, 4);
      part += __shfl_xor(part, 8);
      const float alpha = valid ? 1.0f / (1.0f + __expf(-(part + wab))) : 0.0f;
      const _Float16 ah = (_Float16)alpha;
      const v2h alpha2 = {ah, ah};
#pragma unroll
      for (int i = 0; i < 4; ++i) acc2[i] += alpha2 * prod[i];
    }
  }

#pragma unroll
  for (int i = 0; i < 4; ++i) {
    unsigned x = *(unsigned*)&acc2[i];
    unsigned y = (unsigned)__shfl_xor((int)x, 16);
    acc2[i] += *(v2h*)&y;
    x = *(unsigned*)&acc2[i];
    y = (unsigned)__shfl_xor((int)x, 32);
    acc2[i] += *(v2h*)&y;
  }
  if (l < 16)
    *(f32x4*)(agg + (size_t)node * 128 + d0) = *(f32x4*)acc2;
}

// ---------------------------------------------------------------------------
extern "C" void kernel_launch(void* const* d_in, const int* in_sizes, int n_in,
                              void* d_out, int out_size, void* d_ws, size_t ws_size,
                              hipStream_t stream) {
  const int* q_rel = (const int*)d_in[1];
  const int* r_idx = (const int*)d_in[2];
  const float* hidden = (const float*)d_in[3];
  const int* edge_sub = (const int*)d_in[4];
  const int* edge_rel = (const int*)d_in[5];
  const int* edge_obj = (const int*)d_in[6];
  const float* rela = (const float*)d_in[8];
  const float* Ws = (const float*)d_in[9];
  const float* Wr = (const float*)d_in[10];
  const float* Wqr_w = (const float*)d_in[11];
  const float* Wqr_b = (const float*)d_in[12];
  const float* wa_w = (const float*)d_in[13];
  const float* wa_b = (const float*)d_in[14];
  const float* Wh = (const float*)d_in[15];

  const int E = in_sizes[2];
  const int n_node = in_sizes[3] / 128;
  const int n_rel = in_sizes[8] / 128;
  float* out = (float*)d_out;

  const int nbkt = (n_node + 511) / 512;  // 98

  auto al = [](size_t x) { return (x + 511) & ~(size_t)511; };
  char* ws = (char*)d_ws;
  size_t o = 0;
  _Float16* Hcat = (_Float16*)(ws + o);  o += al((size_t)n_node * 256 * 2);
  _Float16* agg  = (_Float16*)(ws + o);  o += al((size_t)n_node * 128 * 2);
  _Float16* Rcat = (_Float16*)(ws + o);  o += al((size_t)n_rel * 256 * 2);
  _Float16* Rwqrt = (_Float16*)(ws + o); o += al((size_t)n_rel * 128 * 2);
  int* offs = (int*)(ws + o);      o += al((size_t)(n_node + 1) * 4);
  int* bhist = (int*)(ws + o);     o += al((size_t)nbkt * 8 * 4);
  int* bcur = (int*)(ws + o);      o += al((size_t)nbkt * 8 * 4);
  int* bstart = (int*)(ws + o);    o += al((size_t)(nbkt + 1) * 4);
  int2* tmp = (int2*)(ws + o);     o += al((size_t)E * 8);
  int2* ssrq = (int2*)(ws + o);    o += al((size_t)E * 8);

  // --- two-level counting sort ---
  (void)hipMemsetAsync(bhist, 0, (size_t)nbkt * 8 * 4, stream);
  bucket_hist<<<dim3(1024), dim3(256), 0, stream>>>(edge_obj, bhist, E, nbkt);
  bucket_scan<<<dim3(1), dim3(256), 0, stream>>>(bhist, bcur, bstart, offs,
                                                 nbkt, n_node, E);
  bucket_scatter<<<dim3(1024), dim3(256), 0, stream>>>(
      edge_obj, edge_sub, edge_rel, r_idx, q_rel, bcur, tmp, E);
  bucket_sort<<<dim3(nbkt), dim3(256), 0, stream>>>(tmp, bstart, offs, ssrq, n_node);

  // --- unified prep (hidden conv+proj, rela conv+2 proj) ---
  const int hid_blocks = (n_node + 63) / 64;
  const int rel_blocks = (n_rel + 63) / 64;
  prep_gemm<<<dim3(hid_blocks + 2 * rel_blocks), dim3(256), 0, stream>>>(
      hidden, rela, Ws, Wr, Wqr_w, Wqr_b, Hcat, Rcat, Rwqrt,
      n_node, n_rel, hid_blocks, rel_blocks);

  // --- fused attention + aggregation ---
  const int rblocks = (n_node * 64 + 255) / 256;
  reduce_f16<<<dim3(rblocks), dim3(256), 0, stream>>>(
      ssrq, offs, Hcat, Rcat, Rwqrt, wa_w, wa_b, agg, n_node);

  // --- final projection ---
  gemm_final<<<dim3(hid_blocks), dim3(256), 0, stream>>>(agg, Wh, out, n_node);
}

// Round 12
// 227.900 us; speedup vs baseline: 3.4938x; 1.8189x over previous
//
#include <hip/hip_runtime.h>

typedef float f32x4 __attribute__((ext_vector_type(4)));
typedef _Float16 f16x8 __attribute__((ext_vector_type(8)));
typedef _Float16 v2h __attribute__((ext_vector_type(2)));
typedef short s16x2 __attribute__((ext_vector_type(2)));

#define NB 128  // partition blocks; ghist layout [bkt*NB + blk]

__device__ __forceinline__ float hdot2(v2h a, v2h b, float c) {
#if __has_builtin(__builtin_amdgcn_fdot2)
  return __builtin_amdgcn_fdot2(a, b, c, false);
#else
  return c + (float)a[0] * (float)b[0] + (float)a[1] * (float)b[1];
#endif
}

__device__ __forceinline__ v2h relu2(v2h a) {
#if __has_builtin(__builtin_elementwise_max)
  const v2h z = {(_Float16)0, (_Float16)0};
  return __builtin_elementwise_max(a, z);
#else
  const v2h z = {(_Float16)0, (_Float16)0};
  s16x2 m = a > z;
  s16x2 bits = *(s16x2*)&a;
  s16x2 r = bits & m;
  return *(v2h*)&r;
#endif
}

// ---------------------------------------------------------------------------
// K1: per-block LDS histogram of buckets (bucket = obj>>9, 512 nodes each).
// Block b owns contiguous edge chunk; writes ghist[bkt*NB + b]. No atomics
// beyond LDS. No memset needed (every entry written).
// ---------------------------------------------------------------------------
__global__ __launch_bounds__(256) void part_hist(const int* __restrict__ eobj,
                                                 int* __restrict__ ghist,
                                                 int E, int nbkt, int chunk) {
  __shared__ int lh[128];
  const int b = blockIdx.x, t = threadIdx.x;
  for (int i = t; i < nbkt; i += 256) lh[i] = 0;
  __syncthreads();
  const int lo = b * chunk, hi = min(lo + chunk, E);
  for (int i = lo + t; i < hi; i += 256) atomicAdd(&lh[eobj[i] >> 9], 1);
  __syncthreads();
  for (int i = t; i < nbkt; i += 256) ghist[i * NB + b] = lh[i];
}

// ---------------------------------------------------------------------------
// K3: deterministic partition, zero global atomics. Each block recomputes its
// cursor bases from ghist (L2-hot, 98x128 ints): pre = prefix over blocks<b,
// tot = bucket total; LDS scan of tot -> bucket starts. Placement via LDS
// atomics. Block 0 writes bstart[] and offs[n].
// payload.y = rel<<18 | qr<<9 | lobj.
// ---------------------------------------------------------------------------
__global__ __launch_bounds__(256) void part_scatter(
    const int* __restrict__ eobj, const int* __restrict__ esub,
    const int* __restrict__ erel, const int* __restrict__ ridx,
    const int* __restrict__ qrel, const int* __restrict__ ghist,
    int* __restrict__ bstart, int* __restrict__ offs,
    int2* __restrict__ tmp, int E, int n, int nbkt, int chunk) {
  __shared__ int s[128];
  __shared__ int scur[128];
  const int b = blockIdx.x, t = threadIdx.x;

  int pre = 0, tot = 0;
  if (t < nbkt) {
#pragma unroll 8
    for (int k = 0; k < NB; ++k) {
      const int v = ghist[t * NB + k];
      pre += (k < b) ? v : 0;
      tot += v;
    }
  }
  if (t < 128) s[t] = (t < nbkt) ? tot : 0;
  __syncthreads();
  // exclusive scan of bucket totals (128-wide Hillis-Steele)
  if (t < 128) {
    for (int o = 1; o < 128; o <<= 1) {
      const int a = (t >= o) ? s[t - o] : 0;
      __syncthreads();
      s[t] += a;
      __syncthreads();
    }
  } else {
    for (int o = 1; o < 128; o <<= 1) { __syncthreads(); __syncthreads(); }
  }
  if (t < nbkt) {
    const int bucket_start = s[t] - tot;
    scur[t] = bucket_start + pre;
    if (b == 0) bstart[t] = bucket_start;
  }
  if (b == 0 && t == 0) { bstart[nbkt] = E; offs[n] = E; }
  __syncthreads();

  const int lo = b * chunk, hi = min(lo + chunk, E);
  for (int i = lo + t; i < hi; i += 256) {
    const int obj = eobj[i];
    const int bkt = obj >> 9;
    const int p = atomicAdd(&scur[bkt], 1);
    tmp[p] = make_int2(esub[i], (erel[i] << 18) | (qrel[ridx[i]] << 9) | (obj & 511));
  }
}

// ---------------------------------------------------------------------------
// K4: one block per bucket. Count per-node in LDS -> scan -> write offs ->
// scatter into LDS stage -> coalesced write of final (sub, rel<<9|qr) CSR.
// ---------------------------------------------------------------------------
__global__ __launch_bounds__(256) void bucket_sort(
    const int2* __restrict__ tmp, const int* __restrict__ bstart,
    int* __restrict__ offs, int2* __restrict__ ssrq, int n) {
  __shared__ int2 stage[8192];
  __shared__ int scnt[512];
  __shared__ int scur[512];
  const int b = blockIdx.x, t = threadIdx.x;
  const int s0 = bstart[b], s1 = bstart[b + 1];
  const int cnt = s1 - s0;
  const int node0 = b * 512;

  scnt[t] = 0;
  scnt[t + 256] = 0;
  __syncthreads();
  for (int i = t; i < cnt; i += 256) atomicAdd(&scnt[tmp[s0 + i].y & 511], 1);
  __syncthreads();

  const int d0 = scnt[t], d1 = scnt[t + 256];
  __syncthreads();
  for (int o = 1; o < 512; o <<= 1) {
    const int a0 = (t >= o) ? scnt[t - o] : 0;
    const int a1 = (t + 256 >= o) ? scnt[t + 256 - o] : 0;
    __syncthreads();
    scnt[t] += a0;
    scnt[t + 256] += a1;
    __syncthreads();
  }
  const int e0 = scnt[t] - d0, e1 = scnt[t + 256] - d1;
  scur[t] = e0;
  scur[t + 256] = e1;
  if (node0 + t < n) offs[node0 + t] = s0 + e0;
  if (node0 + t + 256 < n) offs[node0 + t + 256] = s0 + e1;
  __syncthreads();

  if (cnt <= 8192) {
    for (int i = t; i < cnt; i += 256) {
      const int2 p = tmp[s0 + i];
      const int q = atomicAdd(&scur[p.y & 511], 1);
      stage[q] = make_int2(p.x, p.y >> 9);
    }
    __syncthreads();
    for (int i = t; i < cnt; i += 256) ssrq[s0 + i] = stage[i];
  } else {
    for (int i = t; i < cnt; i += 256) {
      const int2 p = tmp[s0 + i];
      const int q = atomicAdd(&scur[p.y & 511], 1);
      ssrq[s0 + q] = make_int2(p.x, p.y >> 9);
    }
  }
}

// ---------------------------------------------------------------------------
// Unified prep GEMM (3 roles by block index), W staged f32->fp16 LDS.
// ---------------------------------------------------------------------------
__global__ __launch_bounds__(256) void prep_gemm(
    const float* __restrict__ hidden, const float* __restrict__ rela,
    const float* __restrict__ Ws, const float* __restrict__ Wr,
    const float* __restrict__ Wqr, const float* __restrict__ Wqr_b,
    _Float16* __restrict__ Hcat, _Float16* __restrict__ Rcat,
    _Float16* __restrict__ Rwqrt, int n_node, int n_rel,
    int hid_blocks, int rel_blocks) {
  __shared__ _Float16 sW[16384];
  const int bidx = blockIdx.x;
  const float* A;
  const float* W;
  const float* bias = nullptr;
  _Float16* Lo = nullptr;
  _Float16* Chi;
  int M, bb, ldc, coff;
  if (bidx < hid_blocks) {
    bb = bidx; A = hidden; W = Ws; Lo = Hcat; Chi = Hcat;
    M = n_node; ldc = 256; coff = 128;
  } else if (bidx < hid_blocks + rel_blocks) {
    bb = bidx - hid_blocks; A = rela; W = Wr; Lo = Rcat; Chi = Rcat;
    M = n_rel; ldc = 256; coff = 128;
  } else {
    bb = bidx - hid_blocks - rel_blocks; A = rela; W = Wqr; Chi = Rwqrt;
    bias = Wqr_b; M = n_rel; ldc = 128; coff = 0;
  }

  for (int i = threadIdx.x; i < 16384; i += 256) {
    const int k = i >> 7, c = i & 127;
    sW[(k >> 3) * 1024 + c * 8 + (k & 7)] = (_Float16)W[i];
  }
  __syncthreads();

  const int wv = threadIdx.x >> 6, l = threadIdx.x & 63;
  const int row = bb * 64 + wv * 16 + (l & 15);
  const int kb = (l >> 4) * 8;
  const bool rvalid = row < M;

  f16x8 a[4];
#pragma unroll
  for (int kk = 0; kk < 4; ++kk) {
    f16x8 t = {0, 0, 0, 0, 0, 0, 0, 0};
    if (rvalid) {
      const f32x4 lo = *(const f32x4*)(A + (size_t)row * 128 + kb + 32 * kk);
      const f32x4 hi = *(const f32x4*)(A + (size_t)row * 128 + kb + 32 * kk + 4);
      t[0] = (_Float16)lo[0]; t[1] = (_Float16)lo[1];
      t[2] = (_Float16)lo[2]; t[3] = (_Float16)lo[3];
      t[4] = (_Float16)hi[0]; t[5] = (_Float16)hi[1];
      t[6] = (_Float16)hi[2]; t[7] = (_Float16)hi[3];
      if (Lo) *(f16x8*)(Lo + (size_t)row * 256 + kb + 32 * kk) = t;
    }
    a[kk] = t;
  }

  f32x4 acc[8];
#pragma unroll
  for (int n = 0; n < 8; ++n) acc[n] = (f32x4){0.f, 0.f, 0.f, 0.f};
#pragma unroll
  for (int n = 0; n < 8; ++n)
#pragma unroll
    for (int kk = 0; kk < 4; ++kk) {
      const int kg = 4 * kk + (l >> 4);
      const f16x8 bfrag = *(const f16x8*)(sW + kg * 1024 + (16 * n + (l & 15)) * 8);
      acc[n] = __builtin_amdgcn_mfma_f32_16x16x32_f16(a[kk], bfrag, acc[n], 0, 0, 0);
    }

  const int orow_base = bb * 64 + wv * 16 + (l >> 4) * 4;
#pragma unroll
  for (int n = 0; n < 8; ++n) {
    const int col = 16 * n + (l & 15);
    const float badd = bias ? bias[col] : 0.0f;
#pragma unroll
    for (int r4 = 0; r4 < 4; ++r4) {
      const int orow = orow_base + r4;
      if (orow < M)
        Chi[(size_t)orow * ldc + coff + col] = (_Float16)(acc[n][r4] + badd);
    }
  }
}

// ---------------------------------------------------------------------------
// Final projection: out f32 = agg fp16 @ Wh (Wh staged f32->fp16 LDS).
// ---------------------------------------------------------------------------
__global__ __launch_bounds__(256) void gemm_final(
    const _Float16* __restrict__ agg, const float* __restrict__ Wh,
    float* __restrict__ out, int M) {
  __shared__ _Float16 sW[16384];
  for (int i = threadIdx.x; i < 16384; i += 256) {
    const int k = i >> 7, c = i & 127;
    sW[(k >> 3) * 1024 + c * 8 + (k & 7)] = (_Float16)Wh[i];
  }
  __syncthreads();

  const int wv = threadIdx.x >> 6, l = threadIdx.x & 63;
  const int row = blockIdx.x * 64 + wv * 16 + (l & 15);
  const int kb = (l >> 4) * 8;
  const bool rvalid = row < M;

  f16x8 a[4];
#pragma unroll
  for (int kk = 0; kk < 4; ++kk) {
    f16x8 t = {0, 0, 0, 0, 0, 0, 0, 0};
    if (rvalid) t = *(const f16x8*)(agg + (size_t)row * 128 + kb + 32 * kk);
    a[kk] = t;
  }

  f32x4 acc[8];
#pragma unroll
  for (int n = 0; n < 8; ++n) acc[n] = (f32x4){0.f, 0.f, 0.f, 0.f};
#pragma unroll
  for (int n = 0; n < 8; ++n)
#pragma unroll
    for (int kk = 0; kk < 4; ++kk) {
      const int kg = 4 * kk + (l >> 4);
      const f16x8 bfrag = *(const f16x8*)(sW + kg * 1024 + (16 * n + (l & 15)) * 8);
      acc[n] = __builtin_amdgcn_mfma_f32_16x16x32_f16(a[kk], bfrag, acc[n], 0, 0, 0);
    }

  const int orow_base = blockIdx.x * 64 + wv * 16 + (l >> 4) * 4;
#pragma unroll
  for (int n = 0; n < 8; ++n) {
    const int col = 16 * n + (l & 15);
#pragma unroll
    for (int r4 = 0; r4 < 4; ++r4) {
      const int orow = orow_base + r4;
      if (orow < M) out[(size_t)orow * 128 + col] = acc[n][r4];
    }
  }
}

// ---------------------------------------------------------------------------
// Per-node gather-reduce, fp16 packed math (unchanged from R8).
// ---------------------------------------------------------------------------
__global__ __launch_bounds__(256) void reduce_f16(
    const int2* __restrict__ ssrq, const int* __restrict__ offs,
    const _Float16* __restrict__ Hcat, const _Float16* __restrict__ Rcat,
    const _Float16* __restrict__ Rwqrt, const float* __restrict__ wa_w,
    const float* __restrict__ wa_b_p, _Float16* __restrict__ agg, int n_node) {
  const int node = (blockIdx.x * blockDim.x + threadIdx.x) >> 6;
  if (node >= n_node) return;
  const int l = threadIdx.x & 63;
  const int g = l >> 4;
  const int d0 = (l & 15) * 8;

  v2h wa2[4];
  {
    const float4 w0 = *(const float4*)(wa_w + d0);
    const float4 w1 = *(const float4*)(wa_w + d0 + 4);
    wa2[0] = (v2h){(_Float16)w0.x, (_Float16)w0.y};
    wa2[1] = (v2h){(_Float16)w0.z, (_Float16)w0.w};
    wa2[2] = (v2h){(_Float16)w1.x, (_Float16)w1.y};
    wa2[3] = (v2h){(_Float16)w1.z, (_Float16)w1.w};
  }
  const float wab = wa_b_p[0];

  const int start = offs[node], end = offs[node + 1];
  v2h acc2[4] = {};

  for (int base = start; base < end; base += 64) {
    const int cnt = min(end - base, 64);
    int s_all = 0, rq_all = 0;
    if (l < cnt) { const int2 sr = ssrq[base + l]; s_all = sr.x; rq_all = sr.y; }
    for (int c = 0; c < cnt; c += 4) {
      const int src = c + g;
      const bool valid = src < cnt;
      const int sv = __shfl(s_all, src);
      const int rqv = __shfl(rq_all, src);
      const int rv = rqv >> 9, qv = rqv & 511;

      f32x4 rw = *(const f32x4*)(Hcat + ((size_t)sv << 8) + 128 + d0);
      f32x4 rr = *(const f32x4*)(Rcat + ((size_t)rv << 8) + 128 + d0);
      f32x4 rq = *(const f32x4*)(Rwqrt + ((size_t)qv << 7) + d0);
      f32x4 rh = *(const f32x4*)(Hcat + ((size_t)sv << 8) + d0);
      f32x4 rg = *(const f32x4*)(Rcat + ((size_t)rv << 8) + d0);
      const v2h* hw = (const v2h*)&rw;
      const v2h* hr_ = (const v2h*)&rr;
      const v2h* hq = (const v2h*)&rq;
      const v2h* hh = (const v2h*)&rh;
      const v2h* hg = (const v2h*)&rg;

      float part = 0.0f;
      v2h prod[4];
#pragma unroll
      for (int i = 0; i < 4; ++i) {
        const v2h pre = relu2(hw[i] + hr_[i] + hq[i]);
        part = hdot2(pre, wa2[i], part);
        prod[i] = hh[i] * hg[i];
      }
      part += __shfl_xor(part, 1);
      part += __shfl_xor(part, 2);
      part += __shfl_xor(part, 4);
      part += __shfl_xor(part, 8);
      const float alpha = valid ? 1.0f / (1.0f + __expf(-(part + wab))) : 0.0f;
      const _Float16 ah = (_Float16)alpha;
      const v2h alpha2 = {ah, ah};
#pragma unroll
      for (int i = 0; i < 4; ++i) acc2[i] += alpha2 * prod[i];
    }
  }

#pragma unroll
  for (int i = 0; i < 4; ++i) {
    unsigned x = *(unsigned*)&acc2[i];
    unsigned y = (unsigned)__shfl_xor((int)x, 16);
    acc2[i] += *(v2h*)&y;
    x = *(unsigned*)&acc2[i];
    y = (unsigned)__shfl_xor((int)x, 32);
    acc2[i] += *(v2h*)&y;
  }
  if (l < 16)
    *(f32x4*)(agg + (size_t)node * 128 + d0) = *(f32x4*)acc2;
}

// ---------------------------------------------------------------------------
extern "C" void kernel_launch(void* const* d_in, const int* in_sizes, int n_in,
                              void* d_out, int out_size, void* d_ws, size_t ws_size,
                              hipStream_t stream) {
  const int* q_rel = (const int*)d_in[1];
  const int* r_idx = (const int*)d_in[2];
  const float* hidden = (const float*)d_in[3];
  const int* edge_sub = (const int*)d_in[4];
  const int* edge_rel = (const int*)d_in[5];
  const int* edge_obj = (const int*)d_in[6];
  const float* rela = (const float*)d_in[8];
  const float* Ws = (const float*)d_in[9];
  const float* Wr = (const float*)d_in[10];
  const float* Wqr_w = (const float*)d_in[11];
  const float* Wqr_b = (const float*)d_in[12];
  const float* wa_w = (const float*)d_in[13];
  const float* wa_b = (const float*)d_in[14];
  const float* Wh = (const float*)d_in[15];

  const int E = in_sizes[2];
  const int n_node = in_sizes[3] / 128;
  const int n_rel = in_sizes[8] / 128;
  float* out = (float*)d_out;

  const int nbkt = (n_node + 511) / 512;  // 98
  const int chunk = (E + NB - 1) / NB;

  auto al = [](size_t x) { return (x + 511) & ~(size_t)511; };
  char* ws = (char*)d_ws;
  size_t o = 0;
  _Float16* Hcat = (_Float16*)(ws + o);  o += al((size_t)n_node * 256 * 2);
  _Float16* agg  = (_Float16*)(ws + o);  o += al((size_t)n_node * 128 * 2);
  _Float16* Rcat = (_Float16*)(ws + o);  o += al((size_t)n_rel * 256 * 2);
  _Float16* Rwqrt = (_Float16*)(ws + o); o += al((size_t)n_rel * 128 * 2);
  int* offs = (int*)(ws + o);      o += al((size_t)(n_node + 1) * 4);
  int* ghist = (int*)(ws + o);     o += al((size_t)nbkt * NB * 4);
  int* bstart = (int*)(ws + o);    o += al((size_t)(nbkt + 1) * 4);
  int2* tmp = (int2*)(ws + o);     o += al((size_t)E * 8);
  int2* ssrq = (int2*)(ws + o);    o += al((size_t)E * 8);

  // --- deterministic two-level counting sort (no global atomics) ---
  part_hist<<<dim3(NB), dim3(256), 0, stream>>>(edge_obj, ghist, E, nbkt, chunk);
  part_scatter<<<dim3(NB), dim3(256), 0, stream>>>(
      edge_obj, edge_sub, edge_rel, r_idx, q_rel, ghist, bstart, offs,
      tmp, E, n_node, nbkt, chunk);
  bucket_sort<<<dim3(nbkt), dim3(256), 0, stream>>>(tmp, bstart, offs, ssrq, n_node);

  // --- unified prep (hidden conv+proj, rela conv+2 proj) ---
  const int hid_blocks = (n_node + 63) / 64;
  const int rel_blocks = (n_rel + 63) / 64;
  prep_gemm<<<dim3(hid_blocks + 2 * rel_blocks), dim3(256), 0, stream>>>(
      hidden, rela, Ws, Wr, Wqr_w, Wqr_b, Hcat, Rcat, Rwqrt,
      n_node, n_rel, hid_blocks, rel_blocks);

  // --- fused attention + aggregation ---
  const int rblocks = (n_node * 64 + 255) / 256;
  reduce_f16<<<dim3(rblocks), dim3(256), 0, stream>>>(
      ssrq, offs, Hcat, Rcat, Rwqrt, wa_w, wa_b, agg, n_node);

  // --- final projection ---
  gemm_final<<<dim3(hid_blocks), dim3(256), 0, stream>>>(agg, Wh, out, n_node);
}